// Round 4
// baseline (720.504 us; speedup 1.0000x reference)
//
#include <hip/hip_runtime.h>
#include <stdint.h>

// out[m] = MLP(x[m,:]) where x = inputs^T, inputs is [RC=1024][BA=131072] f32.
// Layer 1 as f16 MFMA: C[M=131072, N=64] = x @ W1.
//
// v4 — global_load_lds staging + 4-block/CU stagger + 1 barrier/chunk:
//  - 256 thr (4 waves), MB=128, grid 1024 -> 4 blocks/CU (40 KiB LDS each,
//    4*40960 = 163840 B = exactly 160 KiB), 16 waves/CU, 4 independent
//    barrier groups per CU for latency stagger.
//  - A staged per 32-k chunk straight global->LDS via
//    __builtin_amdgcn_global_load_lds width=16 (no VGPR round-trip, no
//    ds_writes). Each wave stages 8 k-rows with 4 gloads (2 rows/gload:
//    lanes 0-31 row r, lanes 32-63 row r+1; dest linear 1 KiB). LDS is
//    k-major f32 [k][128]: frag reads Ash[k][w*32+ln] hit 32 distinct
//    banks (2-way half-wave alias = free).
//  - W1 chunk staged as pre-formed f16 B-frags: wave w owns frag w
//    (8 scalar loads -> cvt -> one ds_write_b128). L2-hot.
//  - Double-buffered, ONE sync per chunk: vmcnt(0)+lgkmcnt(0)+s_barrier.
//    Loads issued at chunk top fly under COMPUTE; WRITEW's implicit
//    vmcnt(4) leaves A-gloads in flight. Per-wave vmem queues are
//    identical ([W x8, A x4]) so waitcnt counting is uniform.
//  - Epilogue: per-wave 32x33 LDS transpose, layers 2+3 fp32,
//    halves combined via shfl_xor(32).

#define RC 1024
#define BA 131072
#define D1 64
#define D2 16

#define MB  128           // m per block
#define KC  32            // k per chunk
#define NCH (RC / KC)     // 32 chunks
#define HS  33            // epilogue H row stride (f32)

using f16x8  = __attribute__((ext_vector_type(8))) _Float16;
using f32x16 = __attribute__((ext_vector_type(16))) float;

__device__ __forceinline__ void gld16(const float* g, float* lds) {
    __builtin_amdgcn_global_load_lds(
        (const __attribute__((address_space(1))) void*)g,
        (__attribute__((address_space(3))) void*)lds,
        16, 0, 0);
}

__global__ __launch_bounds__(256, 4) void mlp3_mfma_v4(
    const float* __restrict__ inputs,
    const float* __restrict__ W1,
    const float* __restrict__ b1,
    const float* __restrict__ W2,
    const float* __restrict__ b2,
    const float* __restrict__ W3,
    const float* __restrict__ b3,
    float* __restrict__ out)
{
    __shared__ __align__(16) float Ash[2][KC][MB];   // 32 KiB, k-major f32
    __shared__ __align__(16) f16x8 Wsh[2][4][64];    // 8 KiB: frag(ks*2+nt)[lane]

    const int t  = threadIdx.x;
    const int l  = t & 63;
    const int w  = t >> 6;        // wave 0..3
    const int ln = l & 31;
    const int hi = l >> 5;
    const int mBase = blockIdx.x * MB;

    // W-frag role: wave w stages frag w = ks*2+nt
    const int wks = w >> 1;
    const int wnt = w & 1;
    const int wn  = ln + 32 * wnt;
    const int wkb = wks * 16 + hi * 8;

    float wr[8];                  // W prefetch regs
    f32x16 acc0 = {};
    f32x16 acc1 = {};

    // vmem queue per chunk (identical for every wave): [W x8, A x4]
#define LOADW(c) { \
    const float* q_ = W1 + (size_t)((c) * KC + wkb) * D1 + wn; \
    _Pragma("unroll") for (int u = 0; u < 8; ++u) wr[u] = q_[(size_t)u * D1]; }

    // Wave w stages rows w*8 .. w*8+7. One gload covers 2 rows (1 KiB):
    // lanes 0-31 -> row base+2r (cols ln*4..+3), lanes 32-63 -> row base+2r+1.
#define GLOADA(c, b) { \
    const float* g_ = inputs + (size_t)((c) * KC + w * 8 + hi) * BA + (mBase + (ln << 2)); \
    _Pragma("unroll") for (int r = 0; r < 4; ++r) \
        gld16(g_ + (size_t)(2 * r) * BA, &Ash[b][w * 8 + 2 * r][0]); }

#define WRITEW(b) { \
    f16x8 h_; \
    _Pragma("unroll") for (int u = 0; u < 8; ++u) h_[u] = (_Float16)wr[u]; \
    Wsh[b][w][l] = h_; }   /* implicit vmcnt(4): waits W, leaves A flying */

#define SYNC() { \
    asm volatile("s_waitcnt vmcnt(0) lgkmcnt(0)" ::: "memory"); \
    __builtin_amdgcn_sched_barrier(0); \
    __builtin_amdgcn_s_barrier(); \
    __builtin_amdgcn_sched_barrier(0); }

#define COMPUTE(b) { \
    _Pragma("unroll") for (int ks = 0; ks < 2; ++ks) { \
      float av[8]; \
      _Pragma("unroll") for (int u = 0; u < 8; ++u) \
        av[u] = Ash[b][ks * 16 + hi * 8 + u][w * 32 + ln]; \
      f16x8 a_; \
      _Pragma("unroll") for (int u = 0; u < 8; ++u) a_[u] = (_Float16)av[u]; \
      f16x8 b0_ = Wsh[b][ks * 2 + 0][l]; \
      f16x8 b1_ = Wsh[b][ks * 2 + 1][l]; \
      acc0 = __builtin_amdgcn_mfma_f32_32x32x16_f16(a_, b0_, acc0, 0, 0, 0); \
      acc1 = __builtin_amdgcn_mfma_f32_32x32x16_f16(a_, b1_, acc1, 0, 0, 0); \
    } }

    // ---- prologue: stage chunk 0 ----
    LOADW(0); GLOADA(0, 0);
    WRITEW(0);
    SYNC();

    // ---- main loop: double-buffered, ONE barrier per chunk ----
    for (int c = 0; c < NCH; ++c) {
        const int cur = c & 1;
        const int nxt = cur ^ 1;
        if (c + 1 < NCH) { LOADW(c + 1); GLOADA(c + 1, nxt); }  // fly under COMPUTE
        COMPUTE(cur);
        if (c + 1 < NCH) { WRITEW(nxt); }
        SYNC();   // own A-gloads done + W ds_write drained + rendezvous
    }
#undef LOADW
#undef GLOADA
#undef WRITEW
#undef COMPUTE
#undef SYNC

    // ---- epilogue: per-wave 32x33 transpose, layers 2+3 fp32 ----
    // (loop's final SYNC = all LDS reads complete; Ash reusable)
    float* Hw = (float*)Ash + w * (32 * HS);   // 4 waves * 4224 B, wave-private
    const int mc = ln;
    const int dh = hi;

    float h2[D2];
    #pragma unroll
    for (int e = 0; e < D2; ++e) h2[e] = (dh == 0) ? b2[e] : 0.f;

    // C/D layout (32x32): col(n)=lane&31, row(m)=(r&3)+8*(r>>2)+4*(lane>>5)
#define EPI(ACC, DBASE) { \
    _Pragma("unroll") for (int r = 0; r < 16; ++r) { \
        const int mr = (r & 3) + 8 * (r >> 2) + 4 * dh; \
        Hw[mr * HS + mc] = ACC[r]; \
    } \
    asm volatile("s_waitcnt lgkmcnt(0)" ::: "memory"); \
    __builtin_amdgcn_sched_barrier(0); \
    _Pragma("unroll") for (int dd = 0; dd < 16; ++dd) { \
        const int d = (DBASE) + dh * 16 + dd; \
        float h = Hw[mc * HS + dh * 16 + dd] + b1[d]; \
        h = h > 0.f ? h : 0.f; \
        _Pragma("unroll") for (int e = 0; e < D2; ++e) \
            h2[e] = fmaf(h, W2[d * D2 + e], h2[e]); \
    } \
    asm volatile("s_waitcnt lgkmcnt(0)" ::: "memory"); \
    __builtin_amdgcn_sched_barrier(0); }

    EPI(acc0, 0)    // d = 0..31
    EPI(acc1, 32)   // d = 32..63
#undef EPI

    #pragma unroll
    for (int e = 0; e < D2; ++e) h2[e] += __shfl_xor(h2[e], 32, 64);

    float o = b3[0];
    #pragma unroll
    for (int e = 0; e < D2; ++e) {
        float h = h2[e] > 0.f ? h2[e] : 0.f;
        o = fmaf(h, W3[e], o);
    }
    if (l < 32)
        out[mBase + w * 32 + mc] = o;
}

extern "C" void kernel_launch(void* const* d_in, const int* in_sizes, int n_in,
                              void* d_out, int out_size, void* d_ws, size_t ws_size,
                              hipStream_t stream) {
    const float* inputs = (const float*)d_in[0];
    const float* W1     = (const float*)d_in[1];
    const float* b1     = (const float*)d_in[2];
    const float* W2     = (const float*)d_in[3];
    const float* b2     = (const float*)d_in[4];
    const float* W3     = (const float*)d_in[5];
    const float* b3     = (const float*)d_in[6];
    float* out = (float*)d_out;

    dim3 block(256);
    dim3 grid(BA / MB);   // 1024 blocks -> 4 per CU
    mlp3_mfma_v4<<<grid, block, 0, stream>>>(inputs, W1, b1, W2, b2, W3, b3, out);
}

// Round 5
// 715.317 us; speedup vs baseline: 1.0073x; 1.0073x over previous
//
#include <hip/hip_runtime.h>

// out[m] = MLP(x[m,:]) where x = inputs^T, inputs is [RC=1024][BA=131072] f32.
// Layer 1 as f16 MFMA: C[M=131072, N=64] = x @ W1.
//
// v5 — v1's proven layout + true 2-stage pipeline (loads never drained):
//  - 256 thr (4 waves), MB=128, grid 1024 -> 4 blocks/CU (30 KiB LDS),
//    16 waves/CU. Same global access shape as v1 (256 B contiguous
//    wave-segments, k-strided octets per thread) — the best measured.
//  - A and W1 staged per 32-k chunk into f16 LDS, KS=40 (stride 20 dwords:
//    each b128 wave-access hits all 32 banks exactly 4x — bank-balanced).
//    Fragments read as single ds_read_b128 (v1's layout, not v4's scalar).
//  - Double-buffered LDS + ping-pong register staging (ra/wa, rb/wb):
//    chunk c+2's global loads are issued at the END of chunk c and consumed
//    by WRITE at the end of chunk c+1 — one full chunk of flight time.
//    Barriers are lgkmcnt-only (s_barrier builtin); vmcnt is NEVER manually
//    drained — the compiler inserts counted vmcnt at each ds_write consumer.
//  - Epilogue: v4's two-pass 32x33 transpose + fp32 layers 2+3 (proven).

#define RC 1024
#define BA 131072
#define D1 64
#define D2 16

#define MB  128           // m per block
#define KC  32            // k per chunk
#define NCH (RC / KC)     // 32 chunks
#define KS  40            // padded k-stride (f16): 80 B rows, bank-balanced
#define HS  33            // epilogue H row stride (f32)

using f16x8  = __attribute__((ext_vector_type(8))) _Float16;
using f32x16 = __attribute__((ext_vector_type(16))) float;

__global__ __launch_bounds__(256, 4) void mlp3_mfma_v5(
    const float* __restrict__ inputs,
    const float* __restrict__ W1,
    const float* __restrict__ b1,
    const float* __restrict__ W2,
    const float* __restrict__ b2,
    const float* __restrict__ W3,
    const float* __restrict__ b3,
    float* __restrict__ out)
{
    __shared__ __align__(16) _Float16 Ash[2][MB][KS];   // 20480 B
    __shared__ __align__(16) _Float16 Wsh[2][D1][KS];   // 10240 B

    const int t  = threadIdx.x;
    const int l  = t & 63;
    const int w  = t >> 6;        // wave 0..3
    const int ln = l & 31;
    const int hi = l >> 5;
    const int mBase = blockIdx.x * MB;

    // A-staging role: thread covers m=mA, k-octets {kg*8, 16+kg*8}
    const int mA = t & (MB - 1);
    const int kg = t >> 7;        // 0..1
    // W-staging role: thread covers n=nW, k-octet kg2*8
    const int nW  = t & 63;
    const int kg2 = t >> 6;       // 0..3

    float ra[16], wa[8], rb[16], wb[8];   // ping-pong staging regs
    f32x16 acc0 = {};
    f32x16 acc1 = {};

#define LOADA(c, R) { \
    const float* p_ = inputs + (size_t)((c) * KC + kg * 8) * BA + (mBase + mA); \
    _Pragma("unroll") for (int s = 0; s < 2; ++s) \
      _Pragma("unroll") for (int u = 0; u < 8; ++u) \
        R[s * 8 + u] = p_[(size_t)(s * 16 + u) * BA]; }

#define LOADW(c, R) { \
    const float* q_ = W1 + (size_t)((c) * KC + kg2 * 8) * D1 + nW; \
    _Pragma("unroll") for (int u = 0; u < 8; ++u) R[u] = q_[(size_t)u * D1]; }

#define WRITE(b, RA, RW) { \
    _Pragma("unroll") for (int s = 0; s < 2; ++s) { \
      f16x8 h_; \
      _Pragma("unroll") for (int u = 0; u < 8; ++u) h_[u] = (_Float16)RA[s * 8 + u]; \
      *(f16x8*)&Ash[b][mA][s * 16 + kg * 8] = h_; } \
    { f16x8 h_; \
      _Pragma("unroll") for (int u = 0; u < 8; ++u) h_[u] = (_Float16)RW[u]; \
      *(f16x8*)&Wsh[b][nW][kg2 * 8] = h_; } }

    // lgkm-only rendezvous: LDS writes visible; global prefetch stays in flight.
#define BAR() { asm volatile("s_waitcnt lgkmcnt(0)" ::: "memory"); \
                __builtin_amdgcn_sched_barrier(0); \
                __builtin_amdgcn_s_barrier(); \
                __builtin_amdgcn_sched_barrier(0); }

#define COMPUTE(b) { \
    _Pragma("unroll") for (int ks2 = 0; ks2 < 2; ++ks2) { \
      f16x8 a_  = *(const f16x8*)&Ash[b][w * 32 + ln][ks2 * 16 + hi * 8]; \
      f16x8 b0_ = *(const f16x8*)&Wsh[b][ln]         [ks2 * 16 + hi * 8]; \
      f16x8 b1_ = *(const f16x8*)&Wsh[b][ln + 32]    [ks2 * 16 + hi * 8]; \
      acc0 = __builtin_amdgcn_mfma_f32_32x32x16_f16(a_, b0_, acc0, 0, 0, 0); \
      acc1 = __builtin_amdgcn_mfma_f32_32x32x16_f16(a_, b1_, acc1, 0, 0, 0); \
    } }

    // ---- prologue: chunk 0 staged; chunk 1 in flight ----
    LOADA(0, ra); LOADW(0, wa);
    WRITE(0, ra, wa);                  // counted vmcnt inserted by compiler
    LOADA(1, rb); LOADW(1, wb);
    BAR();

    // ---- main loop, 2 chunks per iteration; loads fly one full chunk ----
    for (int c = 0; c < NCH; c += 2) {
        // even chunk: compute buf0; write chunk c+1 -> buf1; issue c+2
        COMPUTE(0);
        if (c + 1 < NCH) WRITE(1, rb, wb);
        if (c + 2 < NCH) { LOADA(c + 2, ra); LOADW(c + 2, wa); }
        BAR();
        // odd chunk: compute buf1; write chunk c+2 -> buf0; issue c+3
        if (c + 1 < NCH) {
            COMPUTE(1);
            if (c + 2 < NCH) WRITE(0, ra, wa);
            if (c + 3 < NCH) { LOADA(c + 3, rb); LOADW(c + 3, wb); }
            BAR();
        }
    }
#undef LOADA
#undef LOADW
#undef WRITE
#undef COMPUTE

    // ---- epilogue: per-wave two-pass 32x33 transpose, layers 2+3 fp32 ----
    // (final BAR: all LDS reads done; Ash region reusable, wave-private tiles)
    float* Hw = (float*)Ash + w * (32 * HS);   // 4 waves x 4224 B = 16896 B
    const int mc = ln;
    const int dh = hi;

    float h2[D2];
    #pragma unroll
    for (int e = 0; e < D2; ++e) h2[e] = (dh == 0) ? b2[e] : 0.f;

    // C/D layout (32x32): col(n)=lane&31, row(m)=(r&3)+8*(r>>2)+4*(lane>>5)
#define EPI(ACC, DBASE) { \
    _Pragma("unroll") for (int r = 0; r < 16; ++r) { \
        const int mr = (r & 3) + 8 * (r >> 2) + 4 * dh; \
        Hw[mr * HS + mc] = ACC[r]; \
    } \
    asm volatile("s_waitcnt lgkmcnt(0)" ::: "memory"); \
    __builtin_amdgcn_sched_barrier(0); \
    _Pragma("unroll") for (int dd = 0; dd < 16; ++dd) { \
        const int d = (DBASE) + dh * 16 + dd; \
        float h = Hw[mc * HS + dh * 16 + dd] + b1[d]; \
        h = h > 0.f ? h : 0.f; \
        _Pragma("unroll") for (int e = 0; e < D2; ++e) \
            h2[e] = fmaf(h, W2[d * D2 + e], h2[e]); \
    } \
    asm volatile("s_waitcnt lgkmcnt(0)" ::: "memory"); \
    __builtin_amdgcn_sched_barrier(0); }

    EPI(acc0, 0)    // hidden d = 0..31
    EPI(acc1, 32)   // hidden d = 32..63
#undef EPI
#undef BAR

    #pragma unroll
    for (int e = 0; e < D2; ++e) h2[e] += __shfl_xor(h2[e], 32, 64);

    float o = b3[0];
    #pragma unroll
    for (int e = 0; e < D2; ++e) {
        float h = h2[e] > 0.f ? h2[e] : 0.f;
        o = fmaf(h, W3[e], o);
    }
    if (l < 32)
        out[mBase + w * 32 + mc] = o;
}

extern "C" void kernel_launch(void* const* d_in, const int* in_sizes, int n_in,
                              void* d_out, int out_size, void* d_ws, size_t ws_size,
                              hipStream_t stream) {
    const float* inputs = (const float*)d_in[0];
    const float* W1     = (const float*)d_in[1];
    const float* b1     = (const float*)d_in[2];
    const float* W2     = (const float*)d_in[3];
    const float* b2     = (const float*)d_in[4];
    const float* W3     = (const float*)d_in[5];
    const float* b3     = (const float*)d_in[6];
    float* out = (float*)d_out;

    dim3 block(256);
    dim3 grid(BA / MB);   // 1024 blocks -> 4 per CU
    mlp3_mfma_v5<<<grid, block, 0, stream>>>(inputs, W1, b1, W2, b2, W3, b3, out);
}